// Round 13
// baseline (139.085 us; speedup 1.0000x reference)
//
#include <hip/hip_runtime.h>

// RetinaNet loss. A=196608, T=200, C=21; inputs fp32, labels int32, out 3x fp32.
// R12 post-mortem: totals invariant (106.4/105.5/104.4) across 3 structures ->
// base ~66us (43us ws-poison + restores + gaps) + ~34us kernel chain, of which
// ~1/3 is dispatch gaps. R13: 4 kernels -> 2 (prep folded into iou; fin folded
// into loss via device-scope last-block-done), and 2 anchors/thread in iou to
// double VALU work per uniform target s_load batch.

#define CLASSES 21
#define TPB 256
#define G 4               // T-split chunks
#define APT 2             // anchors per thread in iou kernel

// ---- K1: partial IoU argmax per (chunk, anchor-pair). Pure VALU + s_load feed. ----
__global__ __launch_bounds__(TPB, 8)
void iou_kernel(const float4* __restrict__ anc,
                const float4* __restrict__ tbox,
                float* __restrict__ pbI, float* __restrict__ pbU,
                int* __restrict__ pbT,
                float* __restrict__ accums, int* __restrict__ counter,
                int A, int T, int chunk) {
    // zero the K2 accumulators/counter (ws is poisoned 0xAA before every launch;
    // K1 fully precedes K2 in stream order, so this is race-free)
    if (blockIdx.x == 0) {
        if (threadIdx.x < 3) atomicExch(&accums[threadIdx.x], 0.0f);
        else if (threadIdx.x == 3) atomicExch(counter, 0);
    }

    int c  = blockIdx.x & (G - 1);
    int ab = blockIdx.x >> 2;
    int a0 = ab * (TPB * APT) + threadIdx.x;     // anchor 0
    int a1 = a0 + TPB;                           // anchor 1 (coalesced pair)
    if (a0 >= A) return;
    bool has1 = (a1 < A);

    float4 av0 = anc[a0];
    float4 av1 = has1 ? anc[a1] : av0;
    float areaA0 = (av0.z - av0.x) * (av0.w - av0.y);
    float areaA1 = (av1.z - av1.x) * (av1.w - av1.y);

    int t0 = c * chunk;
    int t1 = min(T, t0 + chunk);
    float bI0 = 0.0f, bU0 = 1.0f; int bT0 = t0;  // cross-mult running argmax
    float bI1 = 0.0f, bU1 = 1.0f; int bT1 = t0;
    #pragma unroll 5
    for (int t = t0; t < t1; ++t) {
        float4 tv = tbox[t];                     // wave-uniform -> scalar feed
        float ta = (tv.z - tv.x) * (tv.w - tv.y);
        // anchor 0
        {
            float lx = fmaxf(tv.x, av0.x);
            float ly = fmaxf(tv.y, av0.y);
            float rx = fminf(tv.z, av0.z);
            float ry = fminf(tv.w, av0.w);
            float w = fmaxf(rx - lx, 0.0f);
            float h = fmaxf(ry - ly, 0.0f);
            float inter = w * h;
            float uni = (ta + areaA0) - inter;   // >= ~1e-4 for valid boxes
            bool gt = inter * bU0 > bI0 * uni;   // iou_t > iou_best, exact
            bI0 = gt ? inter : bI0;
            bU0 = gt ? uni : bU0;
            bT0 = gt ? t : bT0;
        }
        // anchor 1
        {
            float lx = fmaxf(tv.x, av1.x);
            float ly = fmaxf(tv.y, av1.y);
            float rx = fminf(tv.z, av1.z);
            float ry = fminf(tv.w, av1.w);
            float w = fmaxf(rx - lx, 0.0f);
            float h = fmaxf(ry - ly, 0.0f);
            float inter = w * h;
            float uni = (ta + areaA1) - inter;
            bool gt = inter * bU1 > bI1 * uni;
            bI1 = gt ? inter : bI1;
            bU1 = gt ? uni : bU1;
            bT1 = gt ? t : bT1;
        }
    }
    size_t o0 = (size_t)c * A + a0;              // coalesced partial writes
    pbI[o0] = bI0; pbU[o0] = bU0; pbT[o0] = bT0;
    if (has1) {
        size_t o1 = o0 + TPB;
        pbI[o1] = bI1; pbU[o1] = bU1; pbT[o1] = bT1;
    }
}

// ---- K2: combine partials + focal + reg + block reduce + last-block finalize ----
__global__ __launch_bounds__(TPB)
void loss_kernel(const float* __restrict__ cls,
                 const float4* __restrict__ box,
                 const float4* __restrict__ anc,
                 const int* __restrict__ labels,
                 const float4* __restrict__ tbox,
                 const float* __restrict__ pbI, const float* __restrict__ pbU,
                 const int* __restrict__ pbT,
                 float* __restrict__ accums, int* __restrict__ counter,
                 float* __restrict__ out,
                 int A) {
    __shared__ float s_cls[TPB * CLASSES];       // 21504 B tile
    int tid = threadIdx.x;
    int a = blockIdx.x * TPB + tid;

    // stage cls tile, coalesced float4 (TPB*CLASSES = 5376 floats, /4 = 1344)
    {
        const float4* g4 = (const float4*)(cls + (size_t)blockIdx.x * TPB * CLASSES);
        float4* s4 = (float4*)s_cls;
        int n4 = (TPB * CLASSES) / 4;
        long long rem = ((long long)A * CLASSES - (long long)blockIdx.x * TPB * CLASSES) / 4;
        int lim4 = (rem < n4) ? (int)rem : n4;
        for (int i = tid; i < lim4; i += TPB) s4[i] = g4[i];
    }
    __syncthreads();

    float cls_p = 0.0f, reg_p = 0.0f, pos_p = 0.0f;

    if (a < A) {
        // combine G partials in chunk order (strict > keeps earlier => first-max)
        float bI = 0.0f, bU = 1.0f;
        int bT = 0;
        #pragma unroll
        for (int c = 0; c < G; ++c) {
            size_t o = (size_t)c * A + a;
            float oI = pbI[o];
            float oU = pbU[o];
            int   oT = pbT[o];
            if (c == 0) { bI = oI; bU = oU; bT = oT; }
            else {
                bool gt = oI * bU > bI * oU;
                bI = gt ? oI : bI;
                bU = gt ? oU : bU;
                bT = gt ? oT : bT;
            }
        }
        bool pos = (bI + bI) >= bU;              // max_iou >= 0.5, division-free

        // ---- focal loss, 21 classes from LDS row (stride 21 -> 2-way, free) ----
        int hot = pos ? labels[bT] : 0;
        const float* crow = s_cls + tid * CLASSES;
        float csum = 0.0f;
        #pragma unroll
        for (int j = 0; j < CLASSES; ++j) {
            float x = crow[j];
            float y = (j == hot) ? -x : x;
            float em = __expf(-fabsf(y));                  // (0,1]
            float sp = fmaxf(y, 0.0f) + __logf(1.0f + em); // softplus(y)
            float r1 = __builtin_amdgcn_rcpf(1.0f + em);
            float sg = (y >= 0.0f) ? r1 : em * r1;         // sigmoid(y)
            float f = sg * sg * sp;
            csum = fmaf(f, (j == hot) ? (1.0f / 3.0f) : 1.0f, csum);
        }
        cls_p = csum * 0.75f;

        // ---- reg loss (positives only, ~14%) ----
        if (pos) {
            pos_p = 1.0f;
            float4 av = anc[a];
            float4 bv = box[a];
            float4 tv = tbox[bT];
            float aw = av.z - av.x, ah = av.w - av.y;
            float acx = (av.x + av.z) * 0.5f, acy = (av.y + av.w) * 0.5f;
            float ep0 = ((bv.x + bv.z) * 0.5f - acx) / aw;
            float ep1 = ((bv.y + bv.w) * 0.5f - acy) / ah;
            float ep2 = __logf((bv.z - bv.x) / aw);
            float ep3 = __logf((bv.w - bv.y) / ah);
            float et0 = ((tv.x + tv.z) * 0.5f - acx) / aw;
            float et1 = ((tv.y + tv.w) * 0.5f - acy) / ah;
            float et2 = __logf((tv.z - tv.x) / aw);
            float et3 = __logf((tv.w - tv.y) / ah);
            float r = 0.0f, d;
            d = fabsf(ep0 - et0); r += (d < 1.0f) ? 0.5f * d * d : d - 0.5f;
            d = fabsf(ep1 - et1); r += (d < 1.0f) ? 0.5f * d * d : d - 0.5f;
            d = fabsf(ep2 - et2); r += (d < 1.0f) ? 0.5f * d * d : d - 0.5f;
            d = fabsf(ep3 - et3); r += (d < 1.0f) ? 0.5f * d * d : d - 0.5f;
            reg_p = r;
        }
    }

    // ---- block reduction: wave shuffle -> LDS ----
    #pragma unroll
    for (int off = 32; off > 0; off >>= 1) {
        cls_p += __shfl_down(cls_p, off, 64);
        reg_p += __shfl_down(reg_p, off, 64);
        pos_p += __shfl_down(pos_p, off, 64);
    }
    __shared__ float red[3][TPB / 64];
    int wave = tid >> 6;
    int lane = tid & 63;
    if (lane == 0) {
        red[0][wave] = cls_p;
        red[1][wave] = reg_p;
        red[2][wave] = pos_p;
    }
    __syncthreads();

    // ---- last-block-done finalize (device-scope atomics; no fin kernel) ----
    __shared__ int s_last;
    if (tid == 0) {
        float c = 0.0f, r = 0.0f, q = 0.0f;
        #pragma unroll
        for (int wv = 0; wv < TPB / 64; ++wv) {
            c += red[0][wv]; r += red[1][wv]; q += red[2][wv];
        }
        atomicAdd(&accums[0], c);
        atomicAdd(&accums[1], r);
        atomicAdd(&accums[2], q);
        __threadfence();                          // make adds visible device-wide
        int old = atomicAdd(counter, 1);
        s_last = (old == gridDim.x - 1) ? 1 : 0;
    }
    __syncthreads();
    if (s_last && tid == 0) {
        // read totals via device-scope atomics (cross-XCD safe)
        float cs = atomicAdd(&accums[0], 0.0f);
        float rs = atomicAdd(&accums[1], 0.0f);
        float qs = atomicAdd(&accums[2], 0.0f);
        float norm = fmaxf(qs, 1.0f);
        float wc = cs / norm;
        float wr = (qs > 0.0f) ? rs / (norm * 4.0f) : 0.0f;
        out[0] = wc + wr;
        out[1] = wc;
        out[2] = wr;
    }
}

extern "C" void kernel_launch(void* const* d_in, const int* in_sizes, int n_in,
                              void* d_out, int out_size, void* d_ws, size_t ws_size,
                              hipStream_t stream) {
    const float* cls  = (const float*)d_in[0];   // [A,21] f32 classification_preds
    const float4* box = (const float4*)d_in[1];  // [A,4]  f32 boxes_preds
    const float4* anc = (const float4*)d_in[2];  // [A,4]  f32 anchors
    const float4* tb  = (const float4*)d_in[3];  // [T,4]  f32 target_boxes
    const int* tl     = (const int*)d_in[4];     // [T]    int32 target_labels

    int A = in_sizes[0] / CLASSES;               // 196608
    int T = in_sizes[4];                         // 200
    int chunk = (T + G - 1) / G;                 // 50

    // ws layout
    float* accums = (float*)d_ws;                                    // [3]
    int*   counter = (int*)(accums + 3);                             // [1]
    float* pbI = (float*)((char*)d_ws + 4096);                       // [G*A]
    float* pbU = pbI + (size_t)G * A;                                // [G*A]
    int*   pbT = (int*)(pbU + (size_t)G * A);                        // [G*A]

    int nb1 = ((A + TPB * APT - 1) / (TPB * APT)) * G;               // 1536
    iou_kernel<<<nb1, TPB, 0, stream>>>(anc, tb, pbI, pbU, pbT,
                                        accums, counter, A, T, chunk);

    int nb2 = (A + TPB - 1) / TPB;                                   // 768
    loss_kernel<<<nb2, TPB, 0, stream>>>(cls, box, anc, tl, tb,
                                         pbI, pbU, pbT,
                                         accums, counter, (float*)d_out, A);
}

// Round 14
// 104.643 us; speedup vs baseline: 1.3291x; 1.3291x over previous
//
#include <hip/hip_runtime.h>

// RetinaNet loss. A=196608, T=200, C=21; inputs fp32, labels int32, out 3x fp32.
// R13 post-mortem: device-fence finalize (atomicAdd + __threadfence per block)
// cost ~40us (loss_kernel 51us @ VALUBusy 8%) -> reverted to R12's partials+fin.
// R14: 3 dispatches (prep folded into iou; fin kept separate), and the iou
// T-chunk loop specialized at compile time (CHUNK=50, full unroll) so the
// target feed becomes batched wide s_loads instead of per-iter load+wait.

#define CLASSES 21
#define TPB 256
#define G 4               // T-split chunks

// ---- K1: partial IoU argmax per (chunk, anchor). Pure VALU + scalar feed. ----
template <int CHUNK>
__global__ __launch_bounds__(TPB)
void iou_kernel_t(const float4* __restrict__ anc,
                  const float4* __restrict__ tbox,
                  float* __restrict__ pbI, float* __restrict__ pbU,
                  int* __restrict__ pbT, int A) {
    int c = blockIdx.x & (G - 1);
    int a = (blockIdx.x >> 2) * TPB + threadIdx.x;
    if (a >= A) return;

    float4 av = anc[a];                          // coalesced 16B/lane
    float areaA = (av.z - av.x) * (av.w - av.y);

    const int t0 = c * CHUNK;
    float bI = 0.0f, bU = 1.0f;                  // cross-mult running argmax
    int bT = t0;
    #pragma unroll
    for (int k = 0; k < CHUNK; ++k) {
        int t = t0 + k;
        float4 tv = tbox[t];                     // uniform + const offsets -> wide s_load
        float ta = (tv.z - tv.x) * (tv.w - tv.y);
        float lx = fmaxf(tv.x, av.x);
        float ly = fmaxf(tv.y, av.y);
        float rx = fminf(tv.z, av.z);
        float ry = fminf(tv.w, av.w);
        float w = fmaxf(rx - lx, 0.0f);
        float h = fmaxf(ry - ly, 0.0f);
        float inter = w * h;
        float uni = (ta + areaA) - inter;        // >= ~1e-4 for valid boxes
        bool gt = inter * bU > bI * uni;         // iou_t > iou_best, exact
        bI = gt ? inter : bI;
        bU = gt ? uni : bU;
        bT = gt ? t : bT;
    }
    size_t o = (size_t)c * A + a;                // coalesced partial writes
    pbI[o] = bI;
    pbU[o] = bU;
    pbT[o] = bT;
}

// generic fallback (runtime chunk) for T != G*CHUNK datasets
__global__ __launch_bounds__(TPB)
void iou_kernel_g(const float4* __restrict__ anc,
                  const float4* __restrict__ tbox,
                  float* __restrict__ pbI, float* __restrict__ pbU,
                  int* __restrict__ pbT, int A, int T, int chunk) {
    int c = blockIdx.x & (G - 1);
    int a = (blockIdx.x >> 2) * TPB + threadIdx.x;
    if (a >= A) return;

    float4 av = anc[a];
    float areaA = (av.z - av.x) * (av.w - av.y);

    int t0 = c * chunk;
    int t1 = min(T, t0 + chunk);
    float bI = 0.0f, bU = 1.0f;
    int bT = t0;
    #pragma unroll 10
    for (int t = t0; t < t1; ++t) {
        float4 tv = tbox[t];
        float ta = (tv.z - tv.x) * (tv.w - tv.y);
        float lx = fmaxf(tv.x, av.x);
        float ly = fmaxf(tv.y, av.y);
        float rx = fminf(tv.z, av.z);
        float ry = fminf(tv.w, av.w);
        float w = fmaxf(rx - lx, 0.0f);
        float h = fmaxf(ry - ly, 0.0f);
        float inter = w * h;
        float uni = (ta + areaA) - inter;
        bool gt = inter * bU > bI * uni;
        bI = gt ? inter : bI;
        bU = gt ? uni : bU;
        bT = gt ? t : bT;
    }
    size_t o = (size_t)c * A + a;
    pbI[o] = bI;
    pbU[o] = bU;
    pbT[o] = bT;
}

// ---- K2: combine partials (chunk order = first-max), focal + reg, block partials ----
__global__ __launch_bounds__(TPB)
void loss_kernel(const float* __restrict__ cls,
                 const float4* __restrict__ box,
                 const float4* __restrict__ anc,
                 const int* __restrict__ labels,
                 const float4* __restrict__ tbox,
                 const float* __restrict__ pbI, const float* __restrict__ pbU,
                 const int* __restrict__ pbT,
                 float* __restrict__ pc, float* __restrict__ pr,
                 float* __restrict__ pp,
                 int A) {
    __shared__ float s_cls[TPB * CLASSES];       // 21504 B tile
    int tid = threadIdx.x;
    int a = blockIdx.x * TPB + tid;

    // stage cls tile, coalesced float4 (TPB*CLASSES = 5376 floats, /4 = 1344)
    {
        const float4* g4 = (const float4*)(cls + (size_t)blockIdx.x * TPB * CLASSES);
        float4* s4 = (float4*)s_cls;
        int n4 = (TPB * CLASSES) / 4;
        long long rem = ((long long)A * CLASSES - (long long)blockIdx.x * TPB * CLASSES) / 4;
        int lim4 = (rem < n4) ? (int)rem : n4;
        for (int i = tid; i < lim4; i += TPB) s4[i] = g4[i];
    }
    __syncthreads();

    float cls_p = 0.0f, reg_p = 0.0f, pos_p = 0.0f;

    if (a < A) {
        // combine G partials in chunk order (strict > keeps earlier => first-max)
        float bI = 0.0f, bU = 1.0f;
        int bT = 0;
        #pragma unroll
        for (int c = 0; c < G; ++c) {
            size_t o = (size_t)c * A + a;
            float oI = pbI[o];
            float oU = pbU[o];
            int   oT = pbT[o];
            if (c == 0) { bI = oI; bU = oU; bT = oT; }
            else {
                bool gt = oI * bU > bI * oU;
                bI = gt ? oI : bI;
                bU = gt ? oU : bU;
                bT = gt ? oT : bT;
            }
        }
        bool pos = (bI + bI) >= bU;              // max_iou >= 0.5, division-free

        // ---- focal loss, 21 classes from LDS row (stride 21 -> 2-way, free) ----
        int hot = pos ? labels[bT] : 0;
        const float* crow = s_cls + tid * CLASSES;
        float csum = 0.0f;
        #pragma unroll
        for (int j = 0; j < CLASSES; ++j) {
            float x = crow[j];
            float y = (j == hot) ? -x : x;
            float em = __expf(-fabsf(y));                  // (0,1]
            float sp = fmaxf(y, 0.0f) + __logf(1.0f + em); // softplus(y)
            float r1 = __builtin_amdgcn_rcpf(1.0f + em);
            float sg = (y >= 0.0f) ? r1 : em * r1;         // sigmoid(y)
            float f = sg * sg * sp;
            csum = fmaf(f, (j == hot) ? (1.0f / 3.0f) : 1.0f, csum);
        }
        cls_p = csum * 0.75f;

        // ---- reg loss (positives only, ~14%) ----
        if (pos) {
            pos_p = 1.0f;
            float4 av = anc[a];
            float4 bv = box[a];
            float4 tv = tbox[bT];
            float aw = av.z - av.x, ah = av.w - av.y;
            float acx = (av.x + av.z) * 0.5f, acy = (av.y + av.w) * 0.5f;
            float ep0 = ((bv.x + bv.z) * 0.5f - acx) / aw;
            float ep1 = ((bv.y + bv.w) * 0.5f - acy) / ah;
            float ep2 = __logf((bv.z - bv.x) / aw);
            float ep3 = __logf((bv.w - bv.y) / ah);
            float et0 = ((tv.x + tv.z) * 0.5f - acx) / aw;
            float et1 = ((tv.y + tv.w) * 0.5f - acy) / ah;
            float et2 = __logf((tv.z - tv.x) / aw);
            float et3 = __logf((tv.w - tv.y) / ah);
            float r = 0.0f, d;
            d = fabsf(ep0 - et0); r += (d < 1.0f) ? 0.5f * d * d : d - 0.5f;
            d = fabsf(ep1 - et1); r += (d < 1.0f) ? 0.5f * d * d : d - 0.5f;
            d = fabsf(ep2 - et2); r += (d < 1.0f) ? 0.5f * d * d : d - 0.5f;
            d = fabsf(ep3 - et3); r += (d < 1.0f) ? 0.5f * d * d : d - 0.5f;
            reg_p = r;
        }
    }

    // ---- block reduction: wave shuffle -> LDS -> per-block partial ----
    #pragma unroll
    for (int off = 32; off > 0; off >>= 1) {
        cls_p += __shfl_down(cls_p, off, 64);
        reg_p += __shfl_down(reg_p, off, 64);
        pos_p += __shfl_down(pos_p, off, 64);
    }
    __shared__ float red[3][TPB / 64];
    int wave = tid >> 6;
    int lane = tid & 63;
    if (lane == 0) {
        red[0][wave] = cls_p;
        red[1][wave] = reg_p;
        red[2][wave] = pos_p;
    }
    __syncthreads();
    if (tid == 0) {
        float c = 0.0f, r = 0.0f, q = 0.0f;
        #pragma unroll
        for (int wv = 0; wv < TPB / 64; ++wv) {
            c += red[0][wv]; r += red[1][wv]; q += red[2][wv];
        }
        pc[blockIdx.x] = c;
        pr[blockIdx.x] = r;
        pp[blockIdx.x] = q;
    }
}

// ---- finalize: reduce per-block partials, write 3 fp32 ----
__global__ __launch_bounds__(TPB)
void fin_kernel(const float* __restrict__ pc,
                const float* __restrict__ pr,
                const float* __restrict__ pp,
                int nb, float* __restrict__ out) {
    int tid = threadIdx.x;
    float c = 0.0f, r = 0.0f, q = 0.0f;
    for (int i = tid; i < nb; i += TPB) {
        c += pc[i]; r += pr[i]; q += pp[i];
    }
    #pragma unroll
    for (int off = 32; off > 0; off >>= 1) {
        c += __shfl_down(c, off, 64);
        r += __shfl_down(r, off, 64);
        q += __shfl_down(q, off, 64);
    }
    __shared__ float red[3][TPB / 64];
    int wave = tid >> 6;
    int lane = tid & 63;
    if (lane == 0) { red[0][wave] = c; red[1][wave] = r; red[2][wave] = q; }
    __syncthreads();
    if (tid == 0) {
        float cs = 0.0f, rs = 0.0f, qs = 0.0f;
        #pragma unroll
        for (int wv = 0; wv < TPB / 64; ++wv) {
            cs += red[0][wv]; rs += red[1][wv]; qs += red[2][wv];
        }
        float norm = fmaxf(qs, 1.0f);
        float wc = cs / norm;
        float wr = (qs > 0.0f) ? rs / (norm * 4.0f) : 0.0f;
        out[0] = wc + wr;
        out[1] = wc;
        out[2] = wr;
    }
}

extern "C" void kernel_launch(void* const* d_in, const int* in_sizes, int n_in,
                              void* d_out, int out_size, void* d_ws, size_t ws_size,
                              hipStream_t stream) {
    const float* cls  = (const float*)d_in[0];   // [A,21] f32 classification_preds
    const float4* box = (const float4*)d_in[1];  // [A,4]  f32 boxes_preds
    const float4* anc = (const float4*)d_in[2];  // [A,4]  f32 anchors
    const float4* tb  = (const float4*)d_in[3];  // [T,4]  f32 target_boxes
    const int* tl     = (const int*)d_in[4];     // [T]    int32 target_labels

    int A = in_sizes[0] / CLASSES;               // 196608
    int T = in_sizes[4];                         // 200

    // ws layout
    float* pbI = (float*)((char*)d_ws + 4096);                       // [G*A]
    float* pbU = pbI + (size_t)G * A;                                // [G*A]
    int*   pbT = (int*)(pbU + (size_t)G * A);                        // [G*A]
    int nb2 = (A + TPB - 1) / TPB;                                   // 768
    float* pc = (float*)(pbT + (size_t)G * A);                       // [nb2]
    float* pr = pc + nb2;
    float* pp = pr + nb2;

    int nb1 = nb2 * G;                                               // 3072
    if (T == 200) {
        iou_kernel_t<50><<<nb1, TPB, 0, stream>>>(anc, tb, pbI, pbU, pbT, A);
    } else {
        int chunk = (T + G - 1) / G;
        iou_kernel_g<<<nb1, TPB, 0, stream>>>(anc, tb, pbI, pbU, pbT, A, T, chunk);
    }

    loss_kernel<<<nb2, TPB, 0, stream>>>(cls, box, anc, tl, tb,
                                         pbI, pbU, pbT, pc, pr, pp, A);

    fin_kernel<<<1, TPB, 0, stream>>>(pc, pr, pp, nb2, (float*)d_out);
}